// Round 9
// baseline (423.298 us; speedup 1.0000x reference)
//
#include <hip/hip_runtime.h>
#include <hip/hip_bf16.h>
#include <stdint.h>

#define NDIM 512
#define NN (NDIM*NDIM)      // 262144 positions
#define CDIM 128
#define LDSP 136            // padded LDS stride (f16 elems): 272B, 16B-mult

typedef __attribute__((ext_vector_type(8))) short short8;
typedef __attribute__((ext_vector_type(4))) short short4v;
typedef __attribute__((ext_vector_type(4))) float f32x4;
typedef __attribute__((ext_vector_type(8))) _Float16 half8;
typedef unsigned long long ull;

__device__ __forceinline__ unsigned short f2h(float f) {
    union { _Float16 h; unsigned short u; } v;
    v.h = (_Float16)f;
    return v.u;
}
__device__ __forceinline__ float h2f(unsigned short u) {
    union { _Float16 h; unsigned short u; } v;
    v.u = u;
    return (float)v.h;
}
__device__ __forceinline__ f32x4 mfma16(short8 a, short8 b, f32x4 c) {
    return __builtin_amdgcn_mfma_f32_16x16x32_f16(
        __builtin_bit_cast(half8, a), __builtin_bit_cast(half8, b), c, 0, 0, 0);
}
__device__ __forceinline__ void gl_lds16(const void* g, void* l) {
    __builtin_amdgcn_global_load_lds((const __attribute__((address_space(1))) void*)g,
                                     (__attribute__((address_space(3))) void*)l,
                                     16, 0, 0);
}

// ---------------- K0: weight prep --------------------------------------------
// Wfrag: 5 proj matrices in MFMA-fragment order (f16). Chunk idx = s*2048 +
// h*1024 + kk*256 + n*64 + lane; holds w_s[k0+e][col], col=h*64+n*16+(lane&15),
// k0=kk*32+(lane>>4)*8.  Wo_t[c][h] = w_o[h][c] (f16).
__global__ void k0_prep(const float* __restrict__ w_ag, const float* __restrict__ w_ap,
                        const float* __restrict__ w_bg, const float* __restrict__ w_bp,
                        const float* __restrict__ w_g,  const float* __restrict__ w_o,
                        unsigned short* __restrict__ Wfrag, unsigned short* __restrict__ Wo_t)
{
    int idx = blockIdx.x * 256 + threadIdx.x;
    if (idx < 10240) {
        int lane = idx & 63;
        int n  = (idx >> 6) & 3;
        int kk = (idx >> 8) & 3;
        int h  = (idx >> 10) & 1;
        int s  = idx >> 11;          // 0..4
        const float* w = (s==0) ? w_ag : (s==1) ? w_ap : (s==2) ? w_bg : (s==3) ? w_bp : w_g;
        int col = h*64 + n*16 + (lane & 15);
        int k0  = kk*32 + (lane >> 4)*8;
        short8 pk;
        #pragma unroll
        for (int e = 0; e < 8; e++)
            pk[e] = (short)f2h(w[(k0 + e)*128 + col]);
        *(short8*)(Wfrag + (size_t)idx*8) = pk;
    } else if (idx < 10240 + 16384) {
        int i2 = idx - 10240;
        int cc = i2 >> 7, hh = i2 & 127;
        Wo_t[i2] = f2h(w_o[hh*128 + cc]);
    }
}

// ---------------- K1: LN_in + 5 projections + activations ------------------------
// 512 threads / 8 waves: waves 0-3 -> a-pair (+g cols 0-63), waves 4-7 -> b-pair
// (+g cols 64-127). Halves the per-block serial chain vs the 256-thread version.
// out: a_t[c][pos], b_t[c][pos] (f16 channel-major, shfl write-combined);
//      g_out[pos][c] (f16, round-6 proven LDS-transpose path)
__global__ __launch_bounds__(512, 4) void k1_proj(
    const float* __restrict__ z, const float* __restrict__ mask,
    const float* __restrict__ lnw, const float* __restrict__ lnb,
    const unsigned short* __restrict__ Wfrag,
    const float* __restrict__ b_ag, const float* __restrict__ b_ap,
    const float* __restrict__ b_bg, const float* __restrict__ b_bp,
    const float* __restrict__ b_g,
    unsigned short* __restrict__ a_t, unsigned short* __restrict__ b_t,
    unsigned short* __restrict__ g_out)
{
    __shared__ unsigned short zb[128*LDSP];   // LN'd z [row][k]; reused as g transpose buf
    __shared__ float mask_s[128];
    __shared__ float lnw_s[128];
    __shared__ float lnb_s[128];
    __shared__ float bias_s[640];

    const int t = threadIdx.x;
    const int pos0 = blockIdx.x * 128;
    const int row4 = t >> 2, q = t & 3;       // LN mapping: 4 threads/row
    const int wave = t >> 6, lane = t & 63;
    const int wl = wave & 3, wg = wave >> 2;  // wave-local row band / wave-group
    const int lr = lane & 15, lh = lane >> 4;

    if (t < 128) {
        lnw_s[t] = lnw[t];
        lnb_s[t] = lnb[t];
        mask_s[t] = mask[pos0 + t];
    }
    for (int i = t; i < 640; i += 512) {
        int s = i >> 7, c = i & 127;
        const float* bp = (s==0) ? b_ag : (s==1) ? b_ap : (s==2) ? b_bg : (s==3) ? b_bp : b_g;
        bias_s[i] = bp[c];
    }

    // ---- load z (4 threads per row), LN over C ----
    float v[32];
    float s0 = 0.f, s1 = 0.f;
    {
        const float* zr = z + (size_t)(pos0 + row4) * CDIM + q * 32;
        #pragma unroll
        for (int i = 0; i < 8; i++) {
            float4 qv = *(const float4*)(zr + i*4);
            v[i*4+0] = qv.x; v[i*4+1] = qv.y; v[i*4+2] = qv.z; v[i*4+3] = qv.w;
        }
        #pragma unroll
        for (int i = 0; i < 32; i++) { s0 += v[i]; s1 += v[i]*v[i]; }
        s0 += __shfl_xor(s0, 1);
        s1 += __shfl_xor(s1, 1);
        s0 += __shfl_xor(s0, 2);
        s1 += __shfl_xor(s1, 2);
    }
    __syncthreads();   // lnw_s/lnb_s/bias/mask ready
    {
        float m  = s0 * (1.f/128.f);
        float va = s1 * (1.f/128.f) - m*m;
        float rs = rsqrtf(va + 1e-5f);
        #pragma unroll
        for (int i = 0; i < 4; i++) {
            short8 pk;
            #pragma unroll
            for (int j = 0; j < 8; j++) {
                int c = q*32 + i*8 + j;
                pk[j] = (short)f2h((v[i*8+j]-m)*rs*lnw_s[c] + lnb_s[c]);
            }
            *(short8*)&zb[row4*LDSP + q*32 + i*8] = pk;
        }
    }
    __syncthreads();   // zb ready

    const int rowA0 = (wl*32 + lr)*LDSP;
    const int rowA1 = (wl*32 + 16 + lr)*LDSP;
    const unsigned short* wfl = Wfrag + (size_t)lane*8;

    // GEMM over a 64-col half of one weight matrix: acc[2][4].
    // 16 B-fragments batch-loaded (static indices -> registers) then 32 MFMA.
    auto gemmh = [&](int s, int h, f32x4 (&acc)[2][4]) {
        const unsigned short* wf = wfl + (size_t)(s*2 + h)*8192;
        short8 wbuf[16];
        #pragma unroll
        for (int i = 0; i < 16; i++)
            wbuf[i] = *(const short8*)(wf + i*512);
        #pragma unroll
        for (int m = 0; m < 2; m++)
            #pragma unroll
            for (int n = 0; n < 4; n++) { f32x4 zz = {0.f,0.f,0.f,0.f}; acc[m][n] = zz; }
        #pragma unroll
        for (int kk = 0; kk < 4; kk++) {
            const int k0 = kk*32 + lh*8;
            short8 af0 = *(const short8*)&zb[rowA0 + k0];
            short8 af1 = *(const short8*)&zb[rowA1 + k0];
            #pragma unroll
            for (int n = 0; n < 4; n++) {
                acc[0][n] = mfma16(af0, wbuf[kk*4 + n], acc[0][n]);
                acc[1][n] = mfma16(af1, wbuf[kk*4 + n], acc[1][n]);
            }
        }
    };

    // gated pair -> dst[c][pos] channel-major; shfl_xor(16) write-combine so each
    // store instr covers full 64B lines per column (no partial-line writes).
    auto pair_half = [&](int sG, int sP, int h, unsigned short* dstg) {
        f32x4 G[2][4], P[2][4];
        gemmh(sG, h, G);
        gemmh(sP, h, P);
        const int odd = lh & 1;
        const int base = wl*32 + lh*4 + (odd ? 12 : 0);
        #pragma unroll
        for (int n = 0; n < 4; n++) {
            int col = h*64 + n*16 + lr;
            float bgv = bias_s[sG*128 + col];
            float bpv = bias_s[sP*128 + col];
            union { short4v v; ull u; } p0, p1;
            #pragma unroll
            for (int r = 0; r < 4; r++) {
                float g0 = 1.f / (1.f + __expf(-(G[0][n][r] + bgv)));
                p0.v[r] = (short)f2h(mask_s[wl*32 + lh*4 + r] * g0 * (P[0][n][r] + bpv));
                float g1 = 1.f / (1.f + __expf(-(G[1][n][r] + bgv)));
                p1.v[r] = (short)f2h(mask_s[wl*32 + 16 + lh*4 + r] * g1 * (P[1][n][r] + bpv));
            }
            ull r0 = __shfl_xor(p0.u, 16);
            ull r1 = __shfl_xor(p1.u, 16);
            union { ull u[2]; short8 v; } outv;
            outv.u[0] = odd ? r1 : p0.u;   // rows base..base+3
            outv.u[1] = odd ? p1.u : r0;   // rows base+4..base+7
            *(short8*)(dstg + (size_t)col*NN + pos0 + base) = outv.v;
        }
    };

    if (wg == 0) {
        pair_half(0, 1, 0, a_t);
        pair_half(0, 1, 1, a_t);
    } else {
        pair_half(2, 3, 0, b_t);
        pair_half(2, 3, 1, b_t);
    }

    // gate g: wave-group wg computes column half wg -> g_out[pos][c] via LDS
    // transpose (round-6 proven barrier placement; zb reused after full sync).
    f32x4 G[2][4];
    gemmh(4, wg, G);
    __syncthreads();   // ALL waves done reading zb before overwrite
    #pragma unroll
    for (int m = 0; m < 2; m++) {
        int rb = wl*32 + m*16 + lh*4;
        #pragma unroll
        for (int n = 0; n < 4; n++) {
            int c0 = wg*64 + n*16 + lr;
            float b0 = bias_s[512 + c0];
            #pragma unroll
            for (int r = 0; r < 4; r++)
                zb[(rb + r)*LDSP + c0] = f2h(1.f / (1.f + __expf(-(G[m][n][r] + b0))));
        }
    }
    __syncthreads();
    {
        const unsigned short* src = zb + row4*LDSP + q*32;
        unsigned short* dst = g_out + (size_t)(pos0 + row4)*CDIM + q*32;
        #pragma unroll
        for (int i = 0; i < 4; i++)
            *(short8*)(dst + i*8) = *(const short8*)(src + i*8);
    }
}

// ---------------- K2: per-channel einsum x[c] = A_c * B_c^T ----------------------
// Round-1 structure verbatim: 128x128 tile, K steps of 64, linear LDS staging.
__global__ __launch_bounds__(256, 2) void k2_einsum(
    const unsigned short* __restrict__ a_t,
    const unsigned short* __restrict__ b_t,
    unsigned short* __restrict__ x_t)
{
    __shared__ unsigned short As[128*64];
    __shared__ unsigned short Bs[128*64];

    const int c  = blockIdx.y;
    const int ti = (blockIdx.x >> 2) * 128;
    const int tj = (blockIdx.x & 3) * 128;
    const int t = threadIdx.x;
    const int wave = t >> 6, lane = t & 63;
    const int lr = lane & 15, lh = lane >> 4;
    const int wm = wave >> 1, wn = wave & 1;

    const unsigned short* Ag = a_t + (size_t)c*NN + (size_t)ti*NDIM;
    const unsigned short* Bg = b_t + (size_t)c*NN + (size_t)tj*NDIM;

    const int srow = wave*32 + (lane >> 3);  // staging row within tile
    const int scol = (lane & 7) * 8;         // staging k-offset (elems)

    f32x4 acc[4][4] = {};

    for (int k0 = 0; k0 < NDIM; k0 += 64) {
        __syncthreads();
        #pragma unroll
        for (int it = 0; it < 4; it++) {
            int r = srow + it*8;
            gl_lds16(Ag + (size_t)r*NDIM + k0 + scol, (void*)(As + (wave*32 + it*8)*64));
            gl_lds16(Bg + (size_t)r*NDIM + k0 + scol, (void*)(Bs + (wave*32 + it*8)*64));
        }
        asm volatile("s_waitcnt vmcnt(0)" ::: "memory");
        __syncthreads();
        #pragma unroll
        for (int kk = 0; kk < 2; kk++) {
            const int kof = kk*32 + lh*8;
            short8 af[4], bfr[4];
            #pragma unroll
            for (int m = 0; m < 4; m++)
                af[m] = *(const short8*)&As[(wm*64 + m*16 + lr)*64 + kof];
            #pragma unroll
            for (int n = 0; n < 4; n++)
                bfr[n] = *(const short8*)&Bs[(wn*64 + n*16 + lr)*64 + kof];
            #pragma unroll
            for (int m = 0; m < 4; m++)
                #pragma unroll
                for (int n = 0; n < 4; n++)
                    acc[m][n] = mfma16(af[m], bfr[n], acc[m][n]);
        }
    }

    #pragma unroll
    for (int m = 0; m < 4; m++) {
        int row = ti + wm*64 + m*16 + lh*4;
        #pragma unroll
        for (int n = 0; n < 4; n++) {
            int col = tj + wn*64 + n*16 + lr;
            unsigned short* dst = x_t + (size_t)c*NN + (size_t)row*NDIM + col;
            #pragma unroll
            for (int r = 0; r < 4; r++)
                dst[(size_t)r*NDIM] = f2h(acc[m][n][r]);
        }
    }
}

// ---------------- K3: LN_out + output projection + gate (round-6 structure) ------
__global__ __launch_bounds__(256, 2) void k3_out(
    const unsigned short* __restrict__ x_t,
    const unsigned short* __restrict__ g_in,
    const unsigned short* __restrict__ Wo_t,
    const float* __restrict__ lnw, const float* __restrict__ lnb,
    const float* __restrict__ b_o,
    float* __restrict__ out)
{
    __shared__ unsigned short xb[128*LDSP];   // x tile [c][pos]; reused for Wo [col][k]
    __shared__ unsigned short zl[128*LDSP];   // LN'd x [pos][c]; reused for g [pos][c]
    __shared__ float lnw_s[128];
    __shared__ float lnb_s[128];
    __shared__ float bo_s[128];

    const int t = threadIdx.x;
    const int pos0 = blockIdx.x * 128;
    const int tid2 = t >> 1, half = t & 1;
    const int wave = t >> 6, lane = t & 63;
    const int lr = lane & 15, lh = lane >> 4;

    if (t < 128) { lnw_s[t] = lnw[t]; lnb_s[t] = lnb[t]; bo_s[t] = b_o[t]; }

    // stage x tile: thread pair per channel row, coalesced
    {
        const unsigned short* src = x_t + (size_t)tid2*NN + pos0 + half*64;
        unsigned short* dst = xb + tid2*LDSP + half*64;
        #pragma unroll
        for (int i = 0; i < 8; i++)
            *(short8*)(dst + i*8) = *(const short8*)(src + i*8);
    }
    __syncthreads();

    // LN over c: 2 threads per pos
    {
        float v[64];
        float s0 = 0.f, s1 = 0.f;
        #pragma unroll
        for (int i = 0; i < 64; i++) {
            float x = h2f(xb[(half*64 + i)*LDSP + tid2]);
            v[i] = x; s0 += x; s1 += x*x;
        }
        s0 += __shfl_xor(s0, 1);
        s1 += __shfl_xor(s1, 1);
        float m  = s0 * (1.f/128.f);
        float va = s1 * (1.f/128.f) - m*m;
        float rs = rsqrtf(va + 1e-5f);
        #pragma unroll
        for (int i = 0; i < 64; i++) {
            int cc = half*64 + i;
            zl[tid2*LDSP + cc] = f2h((v[i]-m)*rs*lnw_s[cc] + lnb_s[cc]);
        }
    }
    __syncthreads();

    // Wo into xb (alias; xb dead now)
    {
        const unsigned short* src = Wo_t + ((size_t)tid2*128 + half*64);
        unsigned short* dst = xb + tid2*LDSP + half*64;
        #pragma unroll
        for (int i = 0; i < 8; i++)
            *(short8*)(dst + i*8) = *(const short8*)(src + i*8);
    }
    __syncthreads();

    f32x4 acc[2][8];
    #pragma unroll
    for (int m = 0; m < 2; m++)
        #pragma unroll
        for (int n = 0; n < 8; n++) { f32x4 zz = {0.f,0.f,0.f,0.f}; acc[m][n] = zz; }

    #pragma unroll
    for (int kk = 0; kk < 4; kk++) {
        const int k0 = kk*32 + lh*8;
        short8 af0 = *(const short8*)&zl[(wave*32 + lr)*LDSP + k0];
        short8 af1 = *(const short8*)&zl[(wave*32 + 16 + lr)*LDSP + k0];
        #pragma unroll
        for (int n = 0; n < 8; n++) {
            short8 bf = *(const short8*)&xb[(n*16 + lr)*LDSP + k0];
            acc[0][n] = mfma16(af0, bf, acc[0][n]);
            acc[1][n] = mfma16(af1, bf, acc[1][n]);
        }
    }
    __syncthreads();

    // g into zl space (zl dead after GEMM)
    {
        const unsigned short* src = g_in + (size_t)(pos0 + tid2)*CDIM + half*64;
        unsigned short* dst = zl + tid2*LDSP + half*64;
        #pragma unroll
        for (int i = 0; i < 8; i++)
            *(short8*)(dst + i*8) = *(const short8*)(src + i*8);
    }
    __syncthreads();

    #pragma unroll
    for (int m = 0; m < 2; m++) {
        int rb = wave*32 + m*16 + lh*4;
        #pragma unroll
        for (int n = 0; n < 8; n++) {
            int col = n*16 + lr;
            float bo = bo_s[col];
            #pragma unroll
            for (int r = 0; r < 4; r++) {
                int row = rb + r;
                float gv = h2f(zl[row*LDSP + col]);
                out[(size_t)(pos0 + row)*CDIM + col] = gv * (acc[m][n][r] + bo);
            }
        }
    }
}

// ---------------- launcher -------------------------------------------------------
extern "C" void kernel_launch(void* const* d_in, const int* in_sizes, int n_in,
                              void* d_out, int out_size, void* d_ws, size_t ws_size,
                              hipStream_t stream) {
    const float* z        = (const float*)d_in[0];
    const float* mask     = (const float*)d_in[1];
    const float* ln_in_w  = (const float*)d_in[2];
    const float* ln_in_b  = (const float*)d_in[3];
    const float* w_ap     = (const float*)d_in[4];
    const float* b_ap     = (const float*)d_in[5];
    const float* w_ag     = (const float*)d_in[6];
    const float* b_ag     = (const float*)d_in[7];
    const float* w_bp     = (const float*)d_in[8];
    const float* b_bp     = (const float*)d_in[9];
    const float* w_bg     = (const float*)d_in[10];
    const float* b_bg     = (const float*)d_in[11];
    const float* ln_out_w = (const float*)d_in[12];
    const float* ln_out_b = (const float*)d_in[13];
    const float* w_o      = (const float*)d_in[14];
    const float* b_o      = (const float*)d_in[15];
    const float* w_g      = (const float*)d_in[16];
    const float* b_g      = (const float*)d_in[17];

    char* ws = (char*)d_ws;
    const size_t BUF = (size_t)NN * 128 * 2;      // 64 MB per f16 buffer
    unsigned short* a_t   = (unsigned short*)(ws);
    unsigned short* b_t   = (unsigned short*)(ws + BUF);
    unsigned short* g_b   = (unsigned short*)(ws + 2*BUF);
    unsigned short* x_t   = (unsigned short*)(ws + 3*BUF);
    unsigned short* Wfrag = (unsigned short*)(ws + 4*BUF);
    unsigned short* Wo_t  = (unsigned short*)(ws + 4*BUF + (size_t)10240*8*2);

    k0_prep<<<104, 256, 0, stream>>>(w_ag, w_ap, w_bg, w_bp, w_g, w_o, Wfrag, Wo_t);
    k1_proj<<<NN/128, 512, 0, stream>>>(z, mask, ln_in_w, ln_in_b, Wfrag,
                                        b_ag, b_ap, b_bg, b_bp, b_g, a_t, b_t, g_b);
    k2_einsum<<<dim3(16, 128), 256, 0, stream>>>(a_t, b_t, x_t);
    k3_out<<<NN/128, 256, 0, stream>>>(x_t, g_b, Wo_t, ln_out_w, ln_out_b, b_o,
                                       (float*)d_out);
}

// Round 10
// 348.128 us; speedup vs baseline: 1.2159x; 1.2159x over previous
//
#include <hip/hip_runtime.h>
#include <hip/hip_bf16.h>
#include <stdint.h>

#define NDIM 512
#define NN (NDIM*NDIM)      // 262144 positions
#define CDIM 128
#define LDSP 136            // padded LDS stride (f16 elems): 272B, 16B-mult

typedef __attribute__((ext_vector_type(8))) short short8;
typedef __attribute__((ext_vector_type(4))) short short4v;
typedef __attribute__((ext_vector_type(4))) float f32x4;
typedef __attribute__((ext_vector_type(8))) _Float16 half8;
typedef unsigned long long ull;

__device__ __forceinline__ unsigned short f2h(float f) {
    union { _Float16 h; unsigned short u; } v;
    v.h = (_Float16)f;
    return v.u;
}
__device__ __forceinline__ float h2f(unsigned short u) {
    union { _Float16 h; unsigned short u; } v;
    v.u = u;
    return (float)v.h;
}
__device__ __forceinline__ f32x4 mfma16(short8 a, short8 b, f32x4 c) {
    return __builtin_amdgcn_mfma_f32_16x16x32_f16(
        __builtin_bit_cast(half8, a), __builtin_bit_cast(half8, b), c, 0, 0, 0);
}
__device__ __forceinline__ void gl_lds16(const void* g, void* l) {
    __builtin_amdgcn_global_load_lds((const __attribute__((address_space(1))) void*)g,
                                     (__attribute__((address_space(3))) void*)l,
                                     16, 0, 0);
}

// ---------------- K0: weight prep --------------------------------------------
// Wfrag: 5 proj matrices in MFMA-fragment order (f16). Chunk idx = s*2048 +
// h*1024 + kk*256 + n*64 + lane; holds w_s[k0+e][col], col=h*64+n*16+(lane&15),
// k0=kk*32+(lane>>4)*8.  Wo_t[c][h] = w_o[h][c] (f16).
__global__ void k0_prep(const float* __restrict__ w_ag, const float* __restrict__ w_ap,
                        const float* __restrict__ w_bg, const float* __restrict__ w_bp,
                        const float* __restrict__ w_g,  const float* __restrict__ w_o,
                        unsigned short* __restrict__ Wfrag, unsigned short* __restrict__ Wo_t)
{
    int idx = blockIdx.x * 256 + threadIdx.x;
    if (idx < 10240) {
        int lane = idx & 63;
        int n  = (idx >> 6) & 3;
        int kk = (idx >> 8) & 3;
        int h  = (idx >> 10) & 1;
        int s  = idx >> 11;          // 0..4
        const float* w = (s==0) ? w_ag : (s==1) ? w_ap : (s==2) ? w_bg : (s==3) ? w_bp : w_g;
        int col = h*64 + n*16 + (lane & 15);
        int k0  = kk*32 + (lane >> 4)*8;
        short8 pk;
        #pragma unroll
        for (int e = 0; e < 8; e++)
            pk[e] = (short)f2h(w[(k0 + e)*128 + col]);
        *(short8*)(Wfrag + (size_t)idx*8) = pk;
    } else if (idx < 10240 + 16384) {
        int i2 = idx - 10240;
        int cc = i2 >> 7, hh = i2 & 127;
        Wo_t[i2] = f2h(w_o[hh*128 + cc]);
    }
}

// ---------------- K1: LN_in + 5 projections + activations ------------------------
// R8 structure, fp16, (256,4) for 4 blocks/CU; wbuf split 8+8 to fit 128 VGPR.
// out: a_t[c][pos], b_t[c][pos] (f16 channel-major, shfl write-combined);
//      g_out[pos][c] (f16, round-6 proven LDS-transpose path)
__global__ __launch_bounds__(256, 4) void k1_proj(
    const float* __restrict__ z, const float* __restrict__ mask,
    const float* __restrict__ lnw, const float* __restrict__ lnb,
    const unsigned short* __restrict__ Wfrag,
    const float* __restrict__ b_ag, const float* __restrict__ b_ap,
    const float* __restrict__ b_bg, const float* __restrict__ b_bp,
    const float* __restrict__ b_g,
    unsigned short* __restrict__ a_t, unsigned short* __restrict__ b_t,
    unsigned short* __restrict__ g_out)
{
    __shared__ unsigned short zb[128*LDSP];   // LN'd z [row][k]; reused as g transpose buf
    __shared__ float mask_s[128];
    __shared__ float lnw_s[128];
    __shared__ float lnb_s[128];
    __shared__ float bias_s[640];

    const int t = threadIdx.x;
    const int pos0 = blockIdx.x * 128;
    const int tid2 = t >> 1, half = t & 1;
    const int wave = t >> 6, lane = t & 63;
    const int lr = lane & 15, lh = lane >> 4;

    if (t < 128) {
        lnw_s[t] = lnw[t];
        lnb_s[t] = lnb[t];
        mask_s[t] = mask[pos0 + t];
    }
    for (int i = t; i < 640; i += 256) {
        int s = i >> 7, c = i & 127;
        const float* bp = (s==0) ? b_ag : (s==1) ? b_ap : (s==2) ? b_bg : (s==3) ? b_bp : b_g;
        bias_s[i] = bp[c];
    }

    // ---- load z (2 threads per row), LN over C ----
    float v[64];
    float s0 = 0.f, s1 = 0.f;
    {
        const float* zr = z + (size_t)(pos0 + tid2) * CDIM + half * 64;
        #pragma unroll
        for (int i = 0; i < 16; i++) {
            float4 q = *(const float4*)(zr + i*4);
            v[i*4+0] = q.x; v[i*4+1] = q.y; v[i*4+2] = q.z; v[i*4+3] = q.w;
        }
        #pragma unroll
        for (int i = 0; i < 64; i++) { s0 += v[i]; s1 += v[i]*v[i]; }
        s0 += __shfl_xor(s0, 1);
        s1 += __shfl_xor(s1, 1);
    }
    __syncthreads();   // lnw_s/lnb_s/bias/mask ready
    {
        float m  = s0 * (1.f/128.f);
        float va = s1 * (1.f/128.f) - m*m;
        float rs = rsqrtf(va + 1e-5f);
        #pragma unroll
        for (int i = 0; i < 8; i++) {
            short8 pk;
            #pragma unroll
            for (int j = 0; j < 8; j++) {
                int c = half*64 + i*8 + j;
                pk[j] = (short)f2h((v[i*8+j]-m)*rs*lnw_s[c] + lnb_s[c]);
            }
            *(short8*)&zb[tid2*LDSP + half*64 + i*8] = pk;
        }
    }
    __syncthreads();   // zb ready

    const int rowA0 = (wave*32 + lr)*LDSP;
    const int rowA1 = (wave*32 + 16 + lr)*LDSP;
    const unsigned short* wfl = Wfrag + (size_t)lane*8;

    // GEMM over a 64-col half of one weight matrix: acc[2][4].
    // B-fragments batch-loaded in two stages of 8 (keeps peak VGPR < 128;
    // each stage = 8 back-to-back global_load_dwordx4, one vmcnt wait).
    auto gemmh = [&](int s, int h, f32x4 (&acc)[2][4]) {
        const unsigned short* wf = wfl + (size_t)(s*2 + h)*8192;
        #pragma unroll
        for (int m = 0; m < 2; m++)
            #pragma unroll
            for (int n = 0; n < 4; n++) { f32x4 zz = {0.f,0.f,0.f,0.f}; acc[m][n] = zz; }
        #pragma unroll
        for (int st = 0; st < 2; st++) {
            short8 wbuf[8];
            #pragma unroll
            for (int i = 0; i < 8; i++)
                wbuf[i] = *(const short8*)(wf + (st*8 + i)*512);
            #pragma unroll
            for (int k2 = 0; k2 < 2; k2++) {
                const int kk = st*2 + k2;
                const int k0 = kk*32 + lh*8;
                short8 af0 = *(const short8*)&zb[rowA0 + k0];
                short8 af1 = *(const short8*)&zb[rowA1 + k0];
                #pragma unroll
                for (int n = 0; n < 4; n++) {
                    acc[0][n] = mfma16(af0, wbuf[k2*4 + n], acc[0][n]);
                    acc[1][n] = mfma16(af1, wbuf[k2*4 + n], acc[1][n]);
                }
            }
        }
    };

    // gated pair -> dst[c][pos] channel-major; shfl_xor(16) write-combine so each
    // store instr covers full 64B lines per column (no partial-line writes).
    auto pair_half = [&](int sG, int sP, int h, unsigned short* dstg) {
        f32x4 G[2][4], P[2][4];
        gemmh(sG, h, G);
        gemmh(sP, h, P);
        const int odd = lh & 1;
        const int base = wave*32 + lh*4 + (odd ? 12 : 0);
        #pragma unroll
        for (int n = 0; n < 4; n++) {
            int col = h*64 + n*16 + lr;
            float bgv = bias_s[sG*128 + col];
            float bpv = bias_s[sP*128 + col];
            union { short4v v; ull u; } p0, p1;
            #pragma unroll
            for (int r = 0; r < 4; r++) {
                float g0 = 1.f / (1.f + __expf(-(G[0][n][r] + bgv)));
                p0.v[r] = (short)f2h(mask_s[wave*32 + lh*4 + r] * g0 * (P[0][n][r] + bpv));
                float g1 = 1.f / (1.f + __expf(-(G[1][n][r] + bgv)));
                p1.v[r] = (short)f2h(mask_s[wave*32 + 16 + lh*4 + r] * g1 * (P[1][n][r] + bpv));
            }
            ull r0 = __shfl_xor(p0.u, 16);
            ull r1 = __shfl_xor(p1.u, 16);
            union { ull u[2]; short8 v; } outv;
            outv.u[0] = odd ? r1 : p0.u;   // rows base..base+3
            outv.u[1] = odd ? p1.u : r0;   // rows base+4..base+7
            *(short8*)(dstg + (size_t)col*NN + pos0 + base) = outv.v;
        }
    };

    pair_half(0, 1, 0, a_t);
    pair_half(0, 1, 1, a_t);
    pair_half(2, 3, 0, b_t);
    pair_half(2, 3, 1, b_t);

    // gate g -> g_out[pos][c] via LDS transpose (round-6 proven path; zb reused)
    f32x4 G0[2][4], G1[2][4];
    gemmh(4, 0, G0);
    gemmh(4, 1, G1);
    __syncthreads();   // all zb reads complete block-wide before overwrite
    #pragma unroll
    for (int m = 0; m < 2; m++) {
        int rb = wave*32 + m*16 + lh*4;
        #pragma unroll
        for (int n = 0; n < 4; n++) {
            int c0 = n*16 + lr;
            int c1 = 64 + n*16 + lr;
            float b0 = bias_s[512 + c0];
            float b1 = bias_s[512 + c1];
            #pragma unroll
            for (int r = 0; r < 4; r++) {
                zb[(rb + r)*LDSP + c0] = f2h(1.f / (1.f + __expf(-(G0[m][n][r] + b0))));
                zb[(rb + r)*LDSP + c1] = f2h(1.f / (1.f + __expf(-(G1[m][n][r] + b1))));
            }
        }
    }
    __syncthreads();
    {
        const unsigned short* src = zb + tid2*LDSP + half*64;
        unsigned short* dst = g_out + (size_t)(pos0 + tid2)*CDIM + half*64;
        #pragma unroll
        for (int i = 0; i < 8; i++)
            *(short8*)(dst + i*8) = *(const short8*)(src + i*8);
    }
}

// ---------------- K2: per-channel einsum x[c] = A_c * B_c^T ----------------------
// Round-1 structure verbatim: 128x128 tile, K steps of 64, linear LDS staging.
__global__ __launch_bounds__(256, 2) void k2_einsum(
    const unsigned short* __restrict__ a_t,
    const unsigned short* __restrict__ b_t,
    unsigned short* __restrict__ x_t)
{
    __shared__ unsigned short As[128*64];
    __shared__ unsigned short Bs[128*64];

    const int c  = blockIdx.y;
    const int ti = (blockIdx.x >> 2) * 128;
    const int tj = (blockIdx.x & 3) * 128;
    const int t = threadIdx.x;
    const int wave = t >> 6, lane = t & 63;
    const int lr = lane & 15, lh = lane >> 4;
    const int wm = wave >> 1, wn = wave & 1;

    const unsigned short* Ag = a_t + (size_t)c*NN + (size_t)ti*NDIM;
    const unsigned short* Bg = b_t + (size_t)c*NN + (size_t)tj*NDIM;

    const int srow = wave*32 + (lane >> 3);  // staging row within tile
    const int scol = (lane & 7) * 8;         // staging k-offset (elems)

    f32x4 acc[4][4] = {};

    for (int k0 = 0; k0 < NDIM; k0 += 64) {
        __syncthreads();
        #pragma unroll
        for (int it = 0; it < 4; it++) {
            int r = srow + it*8;
            gl_lds16(Ag + (size_t)r*NDIM + k0 + scol, (void*)(As + (wave*32 + it*8)*64));
            gl_lds16(Bg + (size_t)r*NDIM + k0 + scol, (void*)(Bs + (wave*32 + it*8)*64));
        }
        asm volatile("s_waitcnt vmcnt(0)" ::: "memory");
        __syncthreads();
        #pragma unroll
        for (int kk = 0; kk < 2; kk++) {
            const int kof = kk*32 + lh*8;
            short8 af[4], bfr[4];
            #pragma unroll
            for (int m = 0; m < 4; m++)
                af[m] = *(const short8*)&As[(wm*64 + m*16 + lr)*64 + kof];
            #pragma unroll
            for (int n = 0; n < 4; n++)
                bfr[n] = *(const short8*)&Bs[(wn*64 + n*16 + lr)*64 + kof];
            #pragma unroll
            for (int m = 0; m < 4; m++)
                #pragma unroll
                for (int n = 0; n < 4; n++)
                    acc[m][n] = mfma16(af[m], bfr[n], acc[m][n]);
        }
    }

    #pragma unroll
    for (int m = 0; m < 4; m++) {
        int row = ti + wm*64 + m*16 + lh*4;
        #pragma unroll
        for (int n = 0; n < 4; n++) {
            int col = tj + wn*64 + n*16 + lr;
            unsigned short* dst = x_t + (size_t)c*NN + (size_t)row*NDIM + col;
            #pragma unroll
            for (int r = 0; r < 4; r++)
                dst[(size_t)r*NDIM] = f2h(acc[m][n][r]);
        }
    }
}

// ---------------- K3: LN_out + output projection + gate (round-6 structure) ------
__global__ __launch_bounds__(256, 2) void k3_out(
    const unsigned short* __restrict__ x_t,
    const unsigned short* __restrict__ g_in,
    const unsigned short* __restrict__ Wo_t,
    const float* __restrict__ lnw, const float* __restrict__ lnb,
    const float* __restrict__ b_o,
    float* __restrict__ out)
{
    __shared__ unsigned short xb[128*LDSP];   // x tile [c][pos]; reused for Wo [col][k]
    __shared__ unsigned short zl[128*LDSP];   // LN'd x [pos][c]; reused for g [pos][c]
    __shared__ float lnw_s[128];
    __shared__ float lnb_s[128];
    __shared__ float bo_s[128];

    const int t = threadIdx.x;
    const int pos0 = blockIdx.x * 128;
    const int tid2 = t >> 1, half = t & 1;
    const int wave = t >> 6, lane = t & 63;
    const int lr = lane & 15, lh = lane >> 4;

    if (t < 128) { lnw_s[t] = lnw[t]; lnb_s[t] = lnb[t]; bo_s[t] = b_o[t]; }

    // stage x tile: thread pair per channel row, coalesced
    {
        const unsigned short* src = x_t + (size_t)tid2*NN + pos0 + half*64;
        unsigned short* dst = xb + tid2*LDSP + half*64;
        #pragma unroll
        for (int i = 0; i < 8; i++)
            *(short8*)(dst + i*8) = *(const short8*)(src + i*8);
    }
    __syncthreads();

    // LN over c: 2 threads per pos
    {
        float v[64];
        float s0 = 0.f, s1 = 0.f;
        #pragma unroll
        for (int i = 0; i < 64; i++) {
            float x = h2f(xb[(half*64 + i)*LDSP + tid2]);
            v[i] = x; s0 += x; s1 += x*x;
        }
        s0 += __shfl_xor(s0, 1);
        s1 += __shfl_xor(s1, 1);
        float m  = s0 * (1.f/128.f);
        float va = s1 * (1.f/128.f) - m*m;
        float rs = rsqrtf(va + 1e-5f);
        #pragma unroll
        for (int i = 0; i < 64; i++) {
            int cc = half*64 + i;
            zl[tid2*LDSP + cc] = f2h((v[i]-m)*rs*lnw_s[cc] + lnb_s[cc]);
        }
    }
    __syncthreads();

    // Wo into xb (alias; xb dead now)
    {
        const unsigned short* src = Wo_t + ((size_t)tid2*128 + half*64);
        unsigned short* dst = xb + tid2*LDSP + half*64;
        #pragma unroll
        for (int i = 0; i < 8; i++)
            *(short8*)(dst + i*8) = *(const short8*)(src + i*8);
    }
    __syncthreads();

    f32x4 acc[2][8];
    #pragma unroll
    for (int m = 0; m < 2; m++)
        #pragma unroll
        for (int n = 0; n < 8; n++) { f32x4 zz = {0.f,0.f,0.f,0.f}; acc[m][n] = zz; }

    #pragma unroll
    for (int kk = 0; kk < 4; kk++) {
        const int k0 = kk*32 + lh*8;
        short8 af0 = *(const short8*)&zl[(wave*32 + lr)*LDSP + k0];
        short8 af1 = *(const short8*)&zl[(wave*32 + 16 + lr)*LDSP + k0];
        #pragma unroll
        for (int n = 0; n < 8; n++) {
            short8 bf = *(const short8*)&xb[(n*16 + lr)*LDSP + k0];
            acc[0][n] = mfma16(af0, bf, acc[0][n]);
            acc[1][n] = mfma16(af1, bf, acc[1][n]);
        }
    }
    __syncthreads();

    // g into zl space (zl dead after GEMM)
    {
        const unsigned short* src = g_in + (size_t)(pos0 + tid2)*CDIM + half*64;
        unsigned short* dst = zl + tid2*LDSP + half*64;
        #pragma unroll
        for (int i = 0; i < 8; i++)
            *(short8*)(dst + i*8) = *(const short8*)(src + i*8);
    }
    __syncthreads();

    #pragma unroll
    for (int m = 0; m < 2; m++) {
        int rb = wave*32 + m*16 + lh*4;
        #pragma unroll
        for (int n = 0; n < 8; n++) {
            int col = n*16 + lr;
            float bo = bo_s[col];
            #pragma unroll
            for (int r = 0; r < 4; r++) {
                int row = rb + r;
                float gv = h2f(zl[row*LDSP + col]);
                out[(size_t)(pos0 + row)*CDIM + col] = gv * (acc[m][n][r] + bo);
            }
        }
    }
}

// ---------------- launcher -------------------------------------------------------
extern "C" void kernel_launch(void* const* d_in, const int* in_sizes, int n_in,
                              void* d_out, int out_size, void* d_ws, size_t ws_size,
                              hipStream_t stream) {
    const float* z        = (const float*)d_in[0];
    const float* mask     = (const float*)d_in[1];
    const float* ln_in_w  = (const float*)d_in[2];
    const float* ln_in_b  = (const float*)d_in[3];
    const float* w_ap     = (const float*)d_in[4];
    const float* b_ap     = (const float*)d_in[5];
    const float* w_ag     = (const float*)d_in[6];
    const float* b_ag     = (const float*)d_in[7];
    const float* w_bp     = (const float*)d_in[8];
    const float* b_bp     = (const float*)d_in[9];
    const float* w_bg     = (const float*)d_in[10];
    const float* b_bg     = (const float*)d_in[11];
    const float* ln_out_w = (const float*)d_in[12];
    const float* ln_out_b = (const float*)d_in[13];
    const float* w_o      = (const float*)d_in[14];
    const float* b_o      = (const float*)d_in[15];
    const float* w_g      = (const float*)d_in[16];
    const float* b_g      = (const float*)d_in[17];

    char* ws = (char*)d_ws;
    const size_t BUF = (size_t)NN * 128 * 2;      // 64 MB per f16 buffer
    unsigned short* a_t   = (unsigned short*)(ws);
    unsigned short* b_t   = (unsigned short*)(ws + BUF);
    unsigned short* g_b   = (unsigned short*)(ws + 2*BUF);
    unsigned short* x_t   = (unsigned short*)(ws + 3*BUF);
    unsigned short* Wfrag = (unsigned short*)(ws + 4*BUF);
    unsigned short* Wo_t  = (unsigned short*)(ws + 4*BUF + (size_t)10240*8*2);

    k0_prep<<<104, 256, 0, stream>>>(w_ag, w_ap, w_bg, w_bp, w_g, w_o, Wfrag, Wo_t);
    k1_proj<<<NN/128, 256, 0, stream>>>(z, mask, ln_in_w, ln_in_b, Wfrag,
                                        b_ag, b_ap, b_bg, b_bp, b_g, a_t, b_t, g_b);
    k2_einsum<<<dim3(16, 128), 256, 0, stream>>>(a_t, b_t, x_t);
    k3_out<<<NN/128, 256, 0, stream>>>(x_t, g_b, Wo_t, ln_out_w, ln_out_b, b_o,
                                       (float*)d_out);
}

// Round 11
// 304.563 us; speedup vs baseline: 1.3899x; 1.1430x over previous
//
#include <hip/hip_runtime.h>
#include <hip/hip_bf16.h>
#include <stdint.h>

#define NDIM 512
#define NN (NDIM*NDIM)      // 262144 positions
#define CDIM 128
#define LDSP 136            // padded LDS stride (f16 elems): 272B, 16B-mult

typedef __attribute__((ext_vector_type(8))) short short8;
typedef __attribute__((ext_vector_type(4))) short short4v;
typedef __attribute__((ext_vector_type(4))) float f32x4;
typedef __attribute__((ext_vector_type(8))) _Float16 half8;
typedef unsigned long long ull;

__device__ __forceinline__ unsigned short f2h(float f) {
    union { _Float16 h; unsigned short u; } v;
    v.h = (_Float16)f;
    return v.u;
}
__device__ __forceinline__ float h2f(unsigned short u) {
    union { _Float16 h; unsigned short u; } v;
    v.u = u;
    return (float)v.h;
}
__device__ __forceinline__ f32x4 mfma16(short8 a, short8 b, f32x4 c) {
    return __builtin_amdgcn_mfma_f32_16x16x32_f16(
        __builtin_bit_cast(half8, a), __builtin_bit_cast(half8, b), c, 0, 0, 0);
}
__device__ __forceinline__ void gl_lds16(const void* g, void* l) {
    __builtin_amdgcn_global_load_lds((const __attribute__((address_space(1))) void*)g,
                                     (__attribute__((address_space(3))) void*)l,
                                     16, 0, 0);
}

// ---------------- K0: weight prep --------------------------------------------
// Wfrag: 5 proj matrices in MFMA-fragment order (f16). Chunk idx = s*2048 +
// h*1024 + kk*256 + n*64 + lane; holds w_s[k0+e][col], col=h*64+n*16+(lane&15),
// k0=kk*32+(lane>>4)*8.  Wo_t[c][h] = w_o[h][c] (f16).
__global__ void k0_prep(const float* __restrict__ w_ag, const float* __restrict__ w_ap,
                        const float* __restrict__ w_bg, const float* __restrict__ w_bp,
                        const float* __restrict__ w_g,  const float* __restrict__ w_o,
                        unsigned short* __restrict__ Wfrag, unsigned short* __restrict__ Wo_t)
{
    int idx = blockIdx.x * 256 + threadIdx.x;
    if (idx < 10240) {
        int lane = idx & 63;
        int n  = (idx >> 6) & 3;
        int kk = (idx >> 8) & 3;
        int h  = (idx >> 10) & 1;
        int s  = idx >> 11;          // 0..4
        const float* w = (s==0) ? w_ag : (s==1) ? w_ap : (s==2) ? w_bg : (s==3) ? w_bp : w_g;
        int col = h*64 + n*16 + (lane & 15);
        int k0  = kk*32 + (lane >> 4)*8;
        short8 pk;
        #pragma unroll
        for (int e = 0; e < 8; e++)
            pk[e] = (short)f2h(w[(k0 + e)*128 + col]);
        *(short8*)(Wfrag + (size_t)idx*8) = pk;
    } else if (idx < 10240 + 16384) {
        int i2 = idx - 10240;
        int cc = i2 >> 7, hh = i2 & 127;
        Wo_t[i2] = f2h(w_o[hh*128 + cc]);
    }
}

// ---------------- K1: LN_in + 5 projections + activations ------------------------
// 512 threads / 8 waves: waves 0-3 -> a-pair (+g cols 0-63), waves 4-7 -> b-pair
// (+g cols 64-127): halves the serial chain. (512,2) leaves VGPR cap at 256 so
// the compiler lands at its natural ~90-120 regs (NO spill; R9's failure was
// the (512,4)-forced 64-reg cap). 2 blocks/CU = 16 waves/CU.
__global__ __launch_bounds__(512, 2) void k1_proj(
    const float* __restrict__ z, const float* __restrict__ mask,
    const float* __restrict__ lnw, const float* __restrict__ lnb,
    const unsigned short* __restrict__ Wfrag,
    const float* __restrict__ b_ag, const float* __restrict__ b_ap,
    const float* __restrict__ b_bg, const float* __restrict__ b_bp,
    const float* __restrict__ b_g,
    unsigned short* __restrict__ a_t, unsigned short* __restrict__ b_t,
    unsigned short* __restrict__ g_out)
{
    __shared__ unsigned short zb[128*LDSP];   // LN'd z [row][k]; reused as g transpose buf
    __shared__ float mask_s[128];
    __shared__ float lnw_s[128];
    __shared__ float lnb_s[128];
    __shared__ float bias_s[640];

    const int t = threadIdx.x;
    const int pos0 = blockIdx.x * 128;
    const int row4 = t >> 2, q = t & 3;       // LN mapping: 4 threads/row
    const int wave = t >> 6, lane = t & 63;
    const int wl = wave & 3, wg = wave >> 2;  // wave-local row band / wave-group
    const int lr = lane & 15, lh = lane >> 4;

    if (t < 128) {
        lnw_s[t] = lnw[t];
        lnb_s[t] = lnb[t];
        mask_s[t] = mask[pos0 + t];
    }
    for (int i = t; i < 640; i += 512) {
        int s = i >> 7, c = i & 127;
        const float* bp = (s==0) ? b_ag : (s==1) ? b_ap : (s==2) ? b_bg : (s==3) ? b_bp : b_g;
        bias_s[i] = bp[c];
    }

    // ---- load z (4 threads per row), LN over C ----
    float v[32];
    float s0 = 0.f, s1 = 0.f;
    {
        const float* zr = z + (size_t)(pos0 + row4) * CDIM + q * 32;
        #pragma unroll
        for (int i = 0; i < 8; i++) {
            float4 qv = *(const float4*)(zr + i*4);
            v[i*4+0] = qv.x; v[i*4+1] = qv.y; v[i*4+2] = qv.z; v[i*4+3] = qv.w;
        }
        #pragma unroll
        for (int i = 0; i < 32; i++) { s0 += v[i]; s1 += v[i]*v[i]; }
        s0 += __shfl_xor(s0, 1);
        s1 += __shfl_xor(s1, 1);
        s0 += __shfl_xor(s0, 2);
        s1 += __shfl_xor(s1, 2);
    }
    __syncthreads();   // lnw_s/lnb_s/bias/mask ready
    {
        float m  = s0 * (1.f/128.f);
        float va = s1 * (1.f/128.f) - m*m;
        float rs = rsqrtf(va + 1e-5f);
        #pragma unroll
        for (int i = 0; i < 4; i++) {
            short8 pk;
            #pragma unroll
            for (int j = 0; j < 8; j++) {
                int c = q*32 + i*8 + j;
                pk[j] = (short)f2h((v[i*8+j]-m)*rs*lnw_s[c] + lnb_s[c]);
            }
            *(short8*)&zb[row4*LDSP + q*32 + i*8] = pk;
        }
    }
    __syncthreads();   // zb ready

    const int rowA0 = (wl*32 + lr)*LDSP;
    const int rowA1 = (wl*32 + 16 + lr)*LDSP;
    const unsigned short* wfl = Wfrag + (size_t)lane*8;

    // GEMM over a 64-col half of one weight matrix: acc[2][4].
    // B-fragments batch-loaded in two stages of 8 (modest register peak;
    // each stage = 8 back-to-back global_load_dwordx4, one vmcnt wait).
    auto gemmh = [&](int s, int h, f32x4 (&acc)[2][4]) {
        const unsigned short* wf = wfl + (size_t)(s*2 + h)*8192;
        #pragma unroll
        for (int m = 0; m < 2; m++)
            #pragma unroll
            for (int n = 0; n < 4; n++) { f32x4 zz = {0.f,0.f,0.f,0.f}; acc[m][n] = zz; }
        #pragma unroll
        for (int st = 0; st < 2; st++) {
            short8 wbuf[8];
            #pragma unroll
            for (int i = 0; i < 8; i++)
                wbuf[i] = *(const short8*)(wf + (st*8 + i)*512);
            #pragma unroll
            for (int k2 = 0; k2 < 2; k2++) {
                const int kk = st*2 + k2;
                const int k0 = kk*32 + lh*8;
                short8 af0 = *(const short8*)&zb[rowA0 + k0];
                short8 af1 = *(const short8*)&zb[rowA1 + k0];
                #pragma unroll
                for (int n = 0; n < 4; n++) {
                    acc[0][n] = mfma16(af0, wbuf[k2*4 + n], acc[0][n]);
                    acc[1][n] = mfma16(af1, wbuf[k2*4 + n], acc[1][n]);
                }
            }
        }
    };

    // gated pair -> dst[c][pos] channel-major; shfl_xor(16) write-combine so each
    // store instr covers full 64B lines per column (no partial-line writes).
    auto pair_half = [&](int sG, int sP, int h, unsigned short* dstg) {
        f32x4 G[2][4], P[2][4];
        gemmh(sG, h, G);
        gemmh(sP, h, P);
        const int odd = lh & 1;
        const int base = wl*32 + lh*4 + (odd ? 12 : 0);
        #pragma unroll
        for (int n = 0; n < 4; n++) {
            int col = h*64 + n*16 + lr;
            float bgv = bias_s[sG*128 + col];
            float bpv = bias_s[sP*128 + col];
            union { short4v v; ull u; } p0, p1;
            #pragma unroll
            for (int r = 0; r < 4; r++) {
                float g0 = 1.f / (1.f + __expf(-(G[0][n][r] + bgv)));
                p0.v[r] = (short)f2h(mask_s[wl*32 + lh*4 + r] * g0 * (P[0][n][r] + bpv));
                float g1 = 1.f / (1.f + __expf(-(G[1][n][r] + bgv)));
                p1.v[r] = (short)f2h(mask_s[wl*32 + 16 + lh*4 + r] * g1 * (P[1][n][r] + bpv));
            }
            ull r0 = __shfl_xor(p0.u, 16);
            ull r1 = __shfl_xor(p1.u, 16);
            union { ull u[2]; short8 v; } outv;
            outv.u[0] = odd ? r1 : p0.u;   // rows base..base+3
            outv.u[1] = odd ? p1.u : r0;   // rows base+4..base+7
            *(short8*)(dstg + (size_t)col*NN + pos0 + base) = outv.v;
        }
    };

    if (wg == 0) {
        pair_half(0, 1, 0, a_t);
        pair_half(0, 1, 1, a_t);
    } else {
        pair_half(2, 3, 0, b_t);
        pair_half(2, 3, 1, b_t);
    }

    // gate g: wave-group wg computes column half wg -> g_out[pos][c] via LDS
    // transpose (round-6 proven barrier placement; zb reused after full sync).
    f32x4 G[2][4];
    gemmh(4, wg, G);
    __syncthreads();   // ALL waves done reading zb before overwrite
    #pragma unroll
    for (int m = 0; m < 2; m++) {
        int rb = wl*32 + m*16 + lh*4;
        #pragma unroll
        for (int n = 0; n < 4; n++) {
            int c0 = wg*64 + n*16 + lr;
            float b0 = bias_s[512 + c0];
            #pragma unroll
            for (int r = 0; r < 4; r++)
                zb[(rb + r)*LDSP + c0] = f2h(1.f / (1.f + __expf(-(G[m][n][r] + b0))));
        }
    }
    __syncthreads();
    {
        const unsigned short* src = zb + row4*LDSP + q*32;
        unsigned short* dst = g_out + (size_t)(pos0 + row4)*CDIM + q*32;
        #pragma unroll
        for (int i = 0; i < 4; i++)
            *(short8*)(dst + i*8) = *(const short8*)(src + i*8);
    }
}

// ---------------- K2: per-channel einsum x[c] = A_c * B_c^T ----------------------
// Round-1 structure verbatim: 128x128 tile, K steps of 64, linear LDS staging.
__global__ __launch_bounds__(256, 2) void k2_einsum(
    const unsigned short* __restrict__ a_t,
    const unsigned short* __restrict__ b_t,
    unsigned short* __restrict__ x_t)
{
    __shared__ unsigned short As[128*64];
    __shared__ unsigned short Bs[128*64];

    const int c  = blockIdx.y;
    const int ti = (blockIdx.x >> 2) * 128;
    const int tj = (blockIdx.x & 3) * 128;
    const int t = threadIdx.x;
    const int wave = t >> 6, lane = t & 63;
    const int lr = lane & 15, lh = lane >> 4;
    const int wm = wave >> 1, wn = wave & 1;

    const unsigned short* Ag = a_t + (size_t)c*NN + (size_t)ti*NDIM;
    const unsigned short* Bg = b_t + (size_t)c*NN + (size_t)tj*NDIM;

    const int srow = wave*32 + (lane >> 3);  // staging row within tile
    const int scol = (lane & 7) * 8;         // staging k-offset (elems)

    f32x4 acc[4][4] = {};

    for (int k0 = 0; k0 < NDIM; k0 += 64) {
        __syncthreads();
        #pragma unroll
        for (int it = 0; it < 4; it++) {
            int r = srow + it*8;
            gl_lds16(Ag + (size_t)r*NDIM + k0 + scol, (void*)(As + (wave*32 + it*8)*64));
            gl_lds16(Bg + (size_t)r*NDIM + k0 + scol, (void*)(Bs + (wave*32 + it*8)*64));
        }
        asm volatile("s_waitcnt vmcnt(0)" ::: "memory");
        __syncthreads();
        #pragma unroll
        for (int kk = 0; kk < 2; kk++) {
            const int kof = kk*32 + lh*8;
            short8 af[4], bfr[4];
            #pragma unroll
            for (int m = 0; m < 4; m++)
                af[m] = *(const short8*)&As[(wm*64 + m*16 + lr)*64 + kof];
            #pragma unroll
            for (int n = 0; n < 4; n++)
                bfr[n] = *(const short8*)&Bs[(wn*64 + n*16 + lr)*64 + kof];
            #pragma unroll
            for (int m = 0; m < 4; m++)
                #pragma unroll
                for (int n = 0; n < 4; n++)
                    acc[m][n] = mfma16(af[m], bfr[n], acc[m][n]);
        }
    }

    #pragma unroll
    for (int m = 0; m < 4; m++) {
        int row = ti + wm*64 + m*16 + lh*4;
        #pragma unroll
        for (int n = 0; n < 4; n++) {
            int col = tj + wn*64 + n*16 + lr;
            unsigned short* dst = x_t + (size_t)c*NN + (size_t)row*NDIM + col;
            #pragma unroll
            for (int r = 0; r < 4; r++)
                dst[(size_t)r*NDIM] = f2h(acc[m][n][r]);
        }
    }
}

// ---------------- K3: LN_out + output projection + gate (round-6 structure) ------
__global__ __launch_bounds__(256, 2) void k3_out(
    const unsigned short* __restrict__ x_t,
    const unsigned short* __restrict__ g_in,
    const unsigned short* __restrict__ Wo_t,
    const float* __restrict__ lnw, const float* __restrict__ lnb,
    const float* __restrict__ b_o,
    float* __restrict__ out)
{
    __shared__ unsigned short xb[128*LDSP];   // x tile [c][pos]; reused for Wo [col][k]
    __shared__ unsigned short zl[128*LDSP];   // LN'd x [pos][c]; reused for g [pos][c]
    __shared__ float lnw_s[128];
    __shared__ float lnb_s[128];
    __shared__ float bo_s[128];

    const int t = threadIdx.x;
    const int pos0 = blockIdx.x * 128;
    const int tid2 = t >> 1, half = t & 1;
    const int wave = t >> 6, lane = t & 63;
    const int lr = lane & 15, lh = lane >> 4;

    if (t < 128) { lnw_s[t] = lnw[t]; lnb_s[t] = lnb[t]; bo_s[t] = b_o[t]; }

    // stage x tile: thread pair per channel row, coalesced
    {
        const unsigned short* src = x_t + (size_t)tid2*NN + pos0 + half*64;
        unsigned short* dst = xb + tid2*LDSP + half*64;
        #pragma unroll
        for (int i = 0; i < 8; i++)
            *(short8*)(dst + i*8) = *(const short8*)(src + i*8);
    }
    __syncthreads();

    // LN over c: 2 threads per pos
    {
        float v[64];
        float s0 = 0.f, s1 = 0.f;
        #pragma unroll
        for (int i = 0; i < 64; i++) {
            float x = h2f(xb[(half*64 + i)*LDSP + tid2]);
            v[i] = x; s0 += x; s1 += x*x;
        }
        s0 += __shfl_xor(s0, 1);
        s1 += __shfl_xor(s1, 1);
        float m  = s0 * (1.f/128.f);
        float va = s1 * (1.f/128.f) - m*m;
        float rs = rsqrtf(va + 1e-5f);
        #pragma unroll
        for (int i = 0; i < 64; i++) {
            int cc = half*64 + i;
            zl[tid2*LDSP + cc] = f2h((v[i]-m)*rs*lnw_s[cc] + lnb_s[cc]);
        }
    }
    __syncthreads();

    // Wo into xb (alias; xb dead now)
    {
        const unsigned short* src = Wo_t + ((size_t)tid2*128 + half*64);
        unsigned short* dst = xb + tid2*LDSP + half*64;
        #pragma unroll
        for (int i = 0; i < 8; i++)
            *(short8*)(dst + i*8) = *(const short8*)(src + i*8);
    }
    __syncthreads();

    f32x4 acc[2][8];
    #pragma unroll
    for (int m = 0; m < 2; m++)
        #pragma unroll
        for (int n = 0; n < 8; n++) { f32x4 zz = {0.f,0.f,0.f,0.f}; acc[m][n] = zz; }

    #pragma unroll
    for (int kk = 0; kk < 4; kk++) {
        const int k0 = kk*32 + lh*8;
        short8 af0 = *(const short8*)&zl[(wave*32 + lr)*LDSP + k0];
        short8 af1 = *(const short8*)&zl[(wave*32 + 16 + lr)*LDSP + k0];
        #pragma unroll
        for (int n = 0; n < 8; n++) {
            short8 bf = *(const short8*)&xb[(n*16 + lr)*LDSP + k0];
            acc[0][n] = mfma16(af0, bf, acc[0][n]);
            acc[1][n] = mfma16(af1, bf, acc[1][n]);
        }
    }
    __syncthreads();

    // g into zl space (zl dead after GEMM)
    {
        const unsigned short* src = g_in + (size_t)(pos0 + tid2)*CDIM + half*64;
        unsigned short* dst = zl + tid2*LDSP + half*64;
        #pragma unroll
        for (int i = 0; i < 8; i++)
            *(short8*)(dst + i*8) = *(const short8*)(src + i*8);
    }
    __syncthreads();

    #pragma unroll
    for (int m = 0; m < 2; m++) {
        int rb = wave*32 + m*16 + lh*4;
        #pragma unroll
        for (int n = 0; n < 8; n++) {
            int col = n*16 + lr;
            float bo = bo_s[col];
            #pragma unroll
            for (int r = 0; r < 4; r++) {
                int row = rb + r;
                float gv = h2f(zl[row*LDSP + col]);
                out[(size_t)(pos0 + row)*CDIM + col] = gv * (acc[m][n][r] + bo);
            }
        }
    }
}

// ---------------- launcher -------------------------------------------------------
extern "C" void kernel_launch(void* const* d_in, const int* in_sizes, int n_in,
                              void* d_out, int out_size, void* d_ws, size_t ws_size,
                              hipStream_t stream) {
    const float* z        = (const float*)d_in[0];
    const float* mask     = (const float*)d_in[1];
    const float* ln_in_w  = (const float*)d_in[2];
    const float* ln_in_b  = (const float*)d_in[3];
    const float* w_ap     = (const float*)d_in[4];
    const float* b_ap     = (const float*)d_in[5];
    const float* w_ag     = (const float*)d_in[6];
    const float* b_ag     = (const float*)d_in[7];
    const float* w_bp     = (const float*)d_in[8];
    const float* b_bp     = (const float*)d_in[9];
    const float* w_bg     = (const float*)d_in[10];
    const float* b_bg     = (const float*)d_in[11];
    const float* ln_out_w = (const float*)d_in[12];
    const float* ln_out_b = (const float*)d_in[13];
    const float* w_o      = (const float*)d_in[14];
    const float* b_o      = (const float*)d_in[15];
    const float* w_g      = (const float*)d_in[16];
    const float* b_g      = (const float*)d_in[17];

    char* ws = (char*)d_ws;
    const size_t BUF = (size_t)NN * 128 * 2;      // 64 MB per f16 buffer
    unsigned short* a_t   = (unsigned short*)(ws);
    unsigned short* b_t   = (unsigned short*)(ws + BUF);
    unsigned short* g_b   = (unsigned short*)(ws + 2*BUF);
    unsigned short* x_t   = (unsigned short*)(ws + 3*BUF);
    unsigned short* Wfrag = (unsigned short*)(ws + 4*BUF);
    unsigned short* Wo_t  = (unsigned short*)(ws + 4*BUF + (size_t)10240*8*2);

    k0_prep<<<104, 256, 0, stream>>>(w_ag, w_ap, w_bg, w_bp, w_g, w_o, Wfrag, Wo_t);
    k1_proj<<<NN/128, 512, 0, stream>>>(z, mask, ln_in_w, ln_in_b, Wfrag,
                                        b_ag, b_ap, b_bg, b_bp, b_g, a_t, b_t, g_b);
    k2_einsum<<<dim3(16, 128), 256, 0, stream>>>(a_t, b_t, x_t);
    k3_out<<<NN/128, 256, 0, stream>>>(x_t, g_b, Wo_t, ln_out_w, ln_out_b, b_o,
                                       (float*)d_out);
}

// Round 12
// 285.500 us; speedup vs baseline: 1.4827x; 1.0668x over previous
//
#include <hip/hip_runtime.h>
#include <hip/hip_bf16.h>
#include <stdint.h>

#define NDIM 512
#define NN (NDIM*NDIM)      // 262144 positions
#define CDIM 128
#define LDSP 136            // padded LDS stride (f16 elems): 272B, 16B-mult

typedef __attribute__((ext_vector_type(8))) short short8;
typedef __attribute__((ext_vector_type(4))) short short4v;
typedef __attribute__((ext_vector_type(4))) float f32x4;
typedef __attribute__((ext_vector_type(8))) _Float16 half8;
typedef unsigned long long ull;

__device__ __forceinline__ unsigned short f2h(float f) {
    union { _Float16 h; unsigned short u; } v;
    v.h = (_Float16)f;
    return v.u;
}
__device__ __forceinline__ float h2f(unsigned short u) {
    union { _Float16 h; unsigned short u; } v;
    v.u = u;
    return (float)v.h;
}
__device__ __forceinline__ f32x4 mfma16(short8 a, short8 b, f32x4 c) {
    return __builtin_amdgcn_mfma_f32_16x16x32_f16(
        __builtin_bit_cast(half8, a), __builtin_bit_cast(half8, b), c, 0, 0, 0);
}
__device__ __forceinline__ void gl_lds16(const void* g, void* l) {
    __builtin_amdgcn_global_load_lds((const __attribute__((address_space(1))) void*)g,
                                     (__attribute__((address_space(3))) void*)l,
                                     16, 0, 0);
}

// ---------------- K0: weight prep --------------------------------------------
// Wfrag: 5 proj matrices in MFMA-fragment order (f16). Chunk idx = s*2048 +
// h*1024 + kk*256 + n*64 + lane; holds w_s[k0+e][col], col=h*64+n*16+(lane&15),
// k0=kk*32+(lane>>4)*8.  Wo_t[c][h] = w_o[h][c] (f16).
__global__ void k0_prep(const float* __restrict__ w_ag, const float* __restrict__ w_ap,
                        const float* __restrict__ w_bg, const float* __restrict__ w_bp,
                        const float* __restrict__ w_g,  const float* __restrict__ w_o,
                        unsigned short* __restrict__ Wfrag, unsigned short* __restrict__ Wo_t)
{
    int idx = blockIdx.x * 256 + threadIdx.x;
    if (idx < 10240) {
        int lane = idx & 63;
        int n  = (idx >> 6) & 3;
        int kk = (idx >> 8) & 3;
        int h  = (idx >> 10) & 1;
        int s  = idx >> 11;          // 0..4
        const float* w = (s==0) ? w_ag : (s==1) ? w_ap : (s==2) ? w_bg : (s==3) ? w_bp : w_g;
        int col = h*64 + n*16 + (lane & 15);
        int k0  = kk*32 + (lane >> 4)*8;
        short8 pk;
        #pragma unroll
        for (int e = 0; e < 8; e++)
            pk[e] = (short)f2h(w[(k0 + e)*128 + col]);
        *(short8*)(Wfrag + (size_t)idx*8) = pk;
    } else if (idx < 10240 + 16384) {
        int i2 = idx - 10240;
        int cc = i2 >> 7, hh = i2 & 127;
        Wo_t[i2] = f2h(w_o[hh*128 + cc]);
    }
}

// ---------------- K1: LN_in + 4 gated projections ---------------------------------
// 256 threads / 4 waves, 64-row tile (4096 blocks): waves 0-1 -> a-pair,
// waves 2-3 -> b-pair.  Per-wave chain = 4 gemmh (g moved to K3).
// out: a_t[c][pos], b_t[c][pos] (f16 channel-major, shfl write-combined);
//      zln[pos][c] (f16) for K3's gate GEMM.
__global__ __launch_bounds__(256, 2) void k1_proj(
    const float* __restrict__ z, const float* __restrict__ mask,
    const float* __restrict__ lnw, const float* __restrict__ lnb,
    const unsigned short* __restrict__ Wfrag,
    const float* __restrict__ b_ag, const float* __restrict__ b_ap,
    const float* __restrict__ b_bg, const float* __restrict__ b_bp,
    unsigned short* __restrict__ a_t, unsigned short* __restrict__ b_t,
    unsigned short* __restrict__ zln)
{
    __shared__ unsigned short zb[64*LDSP];    // LN'd z [row][k] (~17.4 KB)
    __shared__ float mask_s[64];
    __shared__ float lnw_s[128];
    __shared__ float lnb_s[128];
    __shared__ float bias_s[512];

    const int t = threadIdx.x;
    const int pos0 = blockIdx.x * 64;
    const int row4 = t >> 2, q = t & 3;       // LN mapping: 4 threads/row, 64 rows
    const int wave = t >> 6, lane = t & 63;
    const int wl = wave & 1, wg = wave >> 1;  // row band (0-31/32-63) / a-or-b group
    const int lr = lane & 15, lh = lane >> 4;

    if (t < 128) {
        lnw_s[t] = lnw[t];
        lnb_s[t] = lnb[t];
    }
    if (t < 64) mask_s[t] = mask[pos0 + t];
    for (int i = t; i < 512; i += 256) {
        int s = i >> 7, c = i & 127;
        const float* bp = (s==0) ? b_ag : (s==1) ? b_ap : (s==2) ? b_bg : b_bp;
        bias_s[i] = bp[c];
    }

    // ---- load z (4 threads per row), LN over C; write zb + stream zln out ----
    float v[32];
    float s0 = 0.f, s1 = 0.f;
    {
        const float* zr = z + (size_t)(pos0 + row4) * CDIM + q * 32;
        #pragma unroll
        for (int i = 0; i < 8; i++) {
            float4 qv = *(const float4*)(zr + i*4);
            v[i*4+0] = qv.x; v[i*4+1] = qv.y; v[i*4+2] = qv.z; v[i*4+3] = qv.w;
        }
        #pragma unroll
        for (int i = 0; i < 32; i++) { s0 += v[i]; s1 += v[i]*v[i]; }
        s0 += __shfl_xor(s0, 1);
        s1 += __shfl_xor(s1, 1);
        s0 += __shfl_xor(s0, 2);
        s1 += __shfl_xor(s1, 2);
    }
    __syncthreads();   // lnw_s/lnb_s ready
    {
        float m  = s0 * (1.f/128.f);
        float va = s1 * (1.f/128.f) - m*m;
        float rs = rsqrtf(va + 1e-5f);
        unsigned short* zo = zln + (size_t)(pos0 + row4)*CDIM + q*32;
        #pragma unroll
        for (int i = 0; i < 4; i++) {
            short8 pk;
            #pragma unroll
            for (int j = 0; j < 8; j++) {
                int c = q*32 + i*8 + j;
                pk[j] = (short)f2h((v[i*8+j]-m)*rs*lnw_s[c] + lnb_s[c]);
            }
            *(short8*)&zb[row4*LDSP + q*32 + i*8] = pk;
            *(short8*)(zo + i*8) = pk;
        }
    }
    __syncthreads();   // zb ready; no more barriers

    const int rowA0 = (wl*32 + lr)*LDSP;
    const int rowA1 = (wl*32 + 16 + lr)*LDSP;
    const unsigned short* wfl = Wfrag + (size_t)lane*8;

    // GEMM over a 64-col half of one weight matrix: acc[2][4].
    // B-fragments batch-loaded in two stages of 8 (one vmcnt wait per 8).
    auto gemmh = [&](int s, int h, f32x4 (&acc)[2][4]) {
        const unsigned short* wf = wfl + (size_t)(s*2 + h)*8192;
        #pragma unroll
        for (int m = 0; m < 2; m++)
            #pragma unroll
            for (int n = 0; n < 4; n++) { f32x4 zz = {0.f,0.f,0.f,0.f}; acc[m][n] = zz; }
        #pragma unroll
        for (int st = 0; st < 2; st++) {
            short8 wbuf[8];
            #pragma unroll
            for (int i = 0; i < 8; i++)
                wbuf[i] = *(const short8*)(wf + (st*8 + i)*512);
            #pragma unroll
            for (int k2 = 0; k2 < 2; k2++) {
                const int kk = st*2 + k2;
                const int k0 = kk*32 + lh*8;
                short8 af0 = *(const short8*)&zb[rowA0 + k0];
                short8 af1 = *(const short8*)&zb[rowA1 + k0];
                #pragma unroll
                for (int n = 0; n < 4; n++) {
                    acc[0][n] = mfma16(af0, wbuf[k2*4 + n], acc[0][n]);
                    acc[1][n] = mfma16(af1, wbuf[k2*4 + n], acc[1][n]);
                }
            }
        }
    };

    // gated pair -> dst[c][pos] channel-major; shfl_xor(16) write-combine (R7-proven
    // row mapping) so each store covers 16B of consecutive positions per column.
    auto pair_half = [&](int sG, int sP, int h, unsigned short* dstg) {
        f32x4 G[2][4], P[2][4];
        gemmh(sG, h, G);
        gemmh(sP, h, P);
        const int odd = lh & 1;
        const int base = wl*32 + lh*4 + (odd ? 12 : 0);
        #pragma unroll
        for (int n = 0; n < 4; n++) {
            int col = h*64 + n*16 + lr;
            float bgv = bias_s[sG*128 + col];
            float bpv = bias_s[sP*128 + col];
            union { short4v v; ull u; } p0, p1;
            #pragma unroll
            for (int r = 0; r < 4; r++) {
                float g0 = 1.f / (1.f + __expf(-(G[0][n][r] + bgv)));
                p0.v[r] = (short)f2h(mask_s[wl*32 + lh*4 + r] * g0 * (P[0][n][r] + bpv));
                float g1 = 1.f / (1.f + __expf(-(G[1][n][r] + bgv)));
                p1.v[r] = (short)f2h(mask_s[wl*32 + 16 + lh*4 + r] * g1 * (P[1][n][r] + bpv));
            }
            ull r0 = __shfl_xor(p0.u, 16);
            ull r1 = __shfl_xor(p1.u, 16);
            union { ull u[2]; short8 v; } outv;
            outv.u[0] = odd ? r1 : p0.u;   // rows base..base+3
            outv.u[1] = odd ? p1.u : r0;   // rows base+4..base+7
            *(short8*)(dstg + (size_t)col*NN + pos0 + base) = outv.v;
        }
    };

    if (wg == 0) {
        pair_half(0, 1, 0, a_t);
        pair_half(0, 1, 1, a_t);
    } else {
        pair_half(2, 3, 0, b_t);
        pair_half(2, 3, 1, b_t);
    }
}

// ---------------- K2: per-channel einsum x[c] = A_c * B_c^T ----------------------
// Round-1 structure verbatim: 128x128 tile, K steps of 64, linear LDS staging.
__global__ __launch_bounds__(256, 2) void k2_einsum(
    const unsigned short* __restrict__ a_t,
    const unsigned short* __restrict__ b_t,
    unsigned short* __restrict__ x_t)
{
    __shared__ unsigned short As[128*64];
    __shared__ unsigned short Bs[128*64];

    const int c  = blockIdx.y;
    const int ti = (blockIdx.x >> 2) * 128;
    const int tj = (blockIdx.x & 3) * 128;
    const int t = threadIdx.x;
    const int wave = t >> 6, lane = t & 63;
    const int lr = lane & 15, lh = lane >> 4;
    const int wm = wave >> 1, wn = wave & 1;

    const unsigned short* Ag = a_t + (size_t)c*NN + (size_t)ti*NDIM;
    const unsigned short* Bg = b_t + (size_t)c*NN + (size_t)tj*NDIM;

    const int srow = wave*32 + (lane >> 3);  // staging row within tile
    const int scol = (lane & 7) * 8;         // staging k-offset (elems)

    f32x4 acc[4][4] = {};

    for (int k0 = 0; k0 < NDIM; k0 += 64) {
        __syncthreads();
        #pragma unroll
        for (int it = 0; it < 4; it++) {
            int r = srow + it*8;
            gl_lds16(Ag + (size_t)r*NDIM + k0 + scol, (void*)(As + (wave*32 + it*8)*64));
            gl_lds16(Bg + (size_t)r*NDIM + k0 + scol, (void*)(Bs + (wave*32 + it*8)*64));
        }
        asm volatile("s_waitcnt vmcnt(0)" ::: "memory");
        __syncthreads();
        #pragma unroll
        for (int kk = 0; kk < 2; kk++) {
            const int kof = kk*32 + lh*8;
            short8 af[4], bfr[4];
            #pragma unroll
            for (int m = 0; m < 4; m++)
                af[m] = *(const short8*)&As[(wm*64 + m*16 + lr)*64 + kof];
            #pragma unroll
            for (int n = 0; n < 4; n++)
                bfr[n] = *(const short8*)&Bs[(wn*64 + n*16 + lr)*64 + kof];
            #pragma unroll
            for (int m = 0; m < 4; m++)
                #pragma unroll
                for (int n = 0; n < 4; n++)
                    acc[m][n] = mfma16(af[m], bfr[n], acc[m][n]);
        }
    }

    #pragma unroll
    for (int m = 0; m < 4; m++) {
        int row = ti + wm*64 + m*16 + lh*4;
        #pragma unroll
        for (int n = 0; n < 4; n++) {
            int col = tj + wn*64 + n*16 + lr;
            unsigned short* dst = x_t + (size_t)c*NN + (size_t)row*NDIM + col;
            #pragma unroll
            for (int r = 0; r < 4; r++)
                dst[(size_t)r*NDIM] = f2h(acc[m][n][r]);
        }
    }
}

// ---------------- K3: LN_out + out-proj + in-kernel gate GEMM --------------------
// GEMM1: out-proj (zl = LN'd x) x Wo.  GEMM2: g = sigmoid(z_ln @ w_g + b_g),
// with IDENTICAL (row,col)<->acc mapping to GEMM1 — no transpose anywhere.
__global__ __launch_bounds__(256, 2) void k3_out(
    const unsigned short* __restrict__ x_t,
    const unsigned short* __restrict__ zln,
    const unsigned short* __restrict__ Wfrag,
    const unsigned short* __restrict__ Wo_t,
    const float* __restrict__ lnw, const float* __restrict__ lnb,
    const float* __restrict__ b_o, const float* __restrict__ b_g,
    float* __restrict__ out)
{
    __shared__ unsigned short xb[128*LDSP];   // x tile [c][pos]; reused for Wo [col][k]
    __shared__ unsigned short zl[128*LDSP];   // LN'd x [pos][c]; reused for z_ln [pos][c]
    __shared__ float lnw_s[128];
    __shared__ float lnb_s[128];
    __shared__ float bo_s[128];
    __shared__ float bg_s[128];

    const int t = threadIdx.x;
    const int pos0 = blockIdx.x * 128;
    const int tid2 = t >> 1, half = t & 1;
    const int wave = t >> 6, lane = t & 63;
    const int lr = lane & 15, lh = lane >> 4;

    if (t < 128) {
        lnw_s[t] = lnw[t]; lnb_s[t] = lnb[t];
        bo_s[t] = b_o[t];  bg_s[t] = b_g[t];
    }

    // stage x tile: thread pair per channel row, coalesced
    {
        const unsigned short* src = x_t + (size_t)tid2*NN + pos0 + half*64;
        unsigned short* dst = xb + tid2*LDSP + half*64;
        #pragma unroll
        for (int i = 0; i < 8; i++)
            *(short8*)(dst + i*8) = *(const short8*)(src + i*8);
    }
    __syncthreads();

    // LN over c: 2 threads per pos
    {
        float v[64];
        float s0 = 0.f, s1 = 0.f;
        #pragma unroll
        for (int i = 0; i < 64; i++) {
            float x = h2f(xb[(half*64 + i)*LDSP + tid2]);
            v[i] = x; s0 += x; s1 += x*x;
        }
        s0 += __shfl_xor(s0, 1);
        s1 += __shfl_xor(s1, 1);
        float m  = s0 * (1.f/128.f);
        float va = s1 * (1.f/128.f) - m*m;
        float rs = rsqrtf(va + 1e-5f);
        #pragma unroll
        for (int i = 0; i < 64; i++) {
            int cc = half*64 + i;
            zl[tid2*LDSP + cc] = f2h((v[i]-m)*rs*lnw_s[cc] + lnb_s[cc]);
        }
    }
    __syncthreads();

    // Wo into xb (alias; xb dead now)
    {
        const unsigned short* src = Wo_t + ((size_t)tid2*128 + half*64);
        unsigned short* dst = xb + tid2*LDSP + half*64;
        #pragma unroll
        for (int i = 0; i < 8; i++)
            *(short8*)(dst + i*8) = *(const short8*)(src + i*8);
    }
    __syncthreads();

    const int rowA0 = (wave*32 + lr)*LDSP;
    const int rowA1 = (wave*32 + 16 + lr)*LDSP;

    // GEMM1: acc1 = LN(x) @ Wo
    f32x4 acc1[2][8];
    #pragma unroll
    for (int m = 0; m < 2; m++)
        #pragma unroll
        for (int n = 0; n < 8; n++) { f32x4 zz = {0.f,0.f,0.f,0.f}; acc1[m][n] = zz; }
    #pragma unroll
    for (int kk = 0; kk < 4; kk++) {
        const int k0 = kk*32 + lh*8;
        short8 af0 = *(const short8*)&zl[rowA0 + k0];
        short8 af1 = *(const short8*)&zl[rowA1 + k0];
        #pragma unroll
        for (int n = 0; n < 8; n++) {
            short8 bf = *(const short8*)&xb[(n*16 + lr)*LDSP + k0];
            acc1[0][n] = mfma16(af0, bf, acc1[0][n]);
            acc1[1][n] = mfma16(af1, bf, acc1[1][n]);
        }
    }
    __syncthreads();   // all zl reads done

    // z_ln tile into zl (same [pos][c] layout)
    {
        const unsigned short* src = zln + (size_t)(pos0 + tid2)*CDIM + half*64;
        unsigned short* dst = zl + tid2*LDSP + half*64;
        #pragma unroll
        for (int i = 0; i < 8; i++)
            *(short8*)(dst + i*8) = *(const short8*)(src + i*8);
    }
    __syncthreads();

    // GEMM2: acc2 = z_ln @ w_g (B-fragments streamed from Wfrag s=4, K1's pattern)
    f32x4 acc2[2][8];
    #pragma unroll
    for (int m = 0; m < 2; m++)
        #pragma unroll
        for (int n = 0; n < 8; n++) { f32x4 zz = {0.f,0.f,0.f,0.f}; acc2[m][n] = zz; }
    const unsigned short* wfl = Wfrag + (size_t)lane*8;
    #pragma unroll
    for (int h = 0; h < 2; h++) {
        const unsigned short* wf = wfl + (size_t)(8 + h)*8192;   // s=4
        #pragma unroll
        for (int st = 0; st < 2; st++) {
            short8 wbuf[8];
            #pragma unroll
            for (int i = 0; i < 8; i++)
                wbuf[i] = *(const short8*)(wf + (st*8 + i)*512);
            #pragma unroll
            for (int k2 = 0; k2 < 2; k2++) {
                const int kk = st*2 + k2;
                const int k0 = kk*32 + lh*8;
                short8 af0 = *(const short8*)&zl[rowA0 + k0];
                short8 af1 = *(const short8*)&zl[rowA1 + k0];
                #pragma unroll
                for (int n = 0; n < 4; n++) {
                    acc2[0][h*4+n] = mfma16(af0, wbuf[k2*4 + n], acc2[0][h*4+n]);
                    acc2[1][h*4+n] = mfma16(af1, wbuf[k2*4 + n], acc2[1][h*4+n]);
                }
            }
        }
    }

    // epilogue: g = sigmoid(acc2 + bg), out = g * (acc1 + bo)   (f32 path for g)
    #pragma unroll
    for (int m = 0; m < 2; m++) {
        int rb = wave*32 + m*16 + lh*4;
        #pragma unroll
        for (int n = 0; n < 8; n++) {
            int col = n*16 + lr;
            float bo = bo_s[col];
            float bg = bg_s[col];
            #pragma unroll
            for (int r = 0; r < 4; r++) {
                float gv = 1.f / (1.f + __expf(-(acc2[m][n][r] + bg)));
                out[(size_t)(pos0 + rb + r)*CDIM + col] = gv * (acc1[m][n][r] + bo);
            }
        }
    }
}

// ---------------- launcher -------------------------------------------------------
extern "C" void kernel_launch(void* const* d_in, const int* in_sizes, int n_in,
                              void* d_out, int out_size, void* d_ws, size_t ws_size,
                              hipStream_t stream) {
    const float* z        = (const float*)d_in[0];
    const float* mask     = (const float*)d_in[1];
    const float* ln_in_w  = (const float*)d_in[2];
    const float* ln_in_b  = (const float*)d_in[3];
    const float* w_ap     = (const float*)d_in[4];
    const float* b_ap     = (const float*)d_in[5];
    const float* w_ag     = (const float*)d_in[6];
    const float* b_ag     = (const float*)d_in[7];
    const float* w_bp     = (const float*)d_in[8];
    const float* b_bp     = (const float*)d_in[9];
    const float* w_bg     = (const float*)d_in[10];
    const float* b_bg     = (const float*)d_in[11];
    const float* ln_out_w = (const float*)d_in[12];
    const float* ln_out_b = (const float*)d_in[13];
    const float* w_o      = (const float*)d_in[14];
    const float* b_o      = (const float*)d_in[15];
    const float* w_g      = (const float*)d_in[16];
    const float* b_g      = (const float*)d_in[17];

    char* ws = (char*)d_ws;
    const size_t BUF = (size_t)NN * 128 * 2;      // 64 MB per f16 buffer
    unsigned short* a_t   = (unsigned short*)(ws);
    unsigned short* b_t   = (unsigned short*)(ws + BUF);
    unsigned short* zln   = (unsigned short*)(ws + 2*BUF);
    unsigned short* x_t   = (unsigned short*)(ws + 3*BUF);
    unsigned short* Wfrag = (unsigned short*)(ws + 4*BUF);
    unsigned short* Wo_t  = (unsigned short*)(ws + 4*BUF + (size_t)10240*8*2);

    k0_prep<<<104, 256, 0, stream>>>(w_ag, w_ap, w_bg, w_bp, w_g, w_o, Wfrag, Wo_t);
    k1_proj<<<NN/64, 256, 0, stream>>>(z, mask, ln_in_w, ln_in_b, Wfrag,
                                       b_ag, b_ap, b_bg, b_bp, a_t, b_t, zln);
    k2_einsum<<<dim3(16, 128), 256, 0, stream>>>(a_t, b_t, x_t);
    k3_out<<<NN/128, 256, 0, stream>>>(x_t, zln, Wfrag, Wo_t, ln_out_w, ln_out_b,
                                       b_o, b_g, (float*)d_out);
}